// Round 7
// baseline (579.194 us; speedup 1.0000x reference)
//
#include <hip/hip_runtime.h>
#include <math.h>

// 2-layer ReLU RNN, B=256, T=1000 (input 800 + zero pad), H=128, F=5.
// R22: recurrent matvecs moved to the MFMA pipe via REPLICATED-B.
// History: R20 (377us rocprof) = 8 waves, fdot2 engines + per-step barrier.
// R21 (462us) = 4 self-contained waves, barrier/2steps -> 750cyc/step naked
// latency (1 wave/SIMD, no TLP). VALU floor for a 128x128 matvec is 128
// fdot2 = 256 cyc issue/wave; MFMA does it in 32 inst (~155cyc, separate
// pipe) IF the B operand is the h vector REPLICATED over all 16 columns:
// bf[kt][j] = h[kt*32+(lane>>4)*8+j] (same for all lane&15 -> 4 distinct
// addrs, broadcast ds_read_b128). All D columns equal -> n-layout immune;
// lane picks its 2 owned rows from acc[mt][reg] via an unrolled cndmask
// chain (mt = (lane&15)>>1 is runtime; rule-#20-safe static indexing).
// A/k fragment maps = R20-verified; C/D row map = m89-verified (used by the
// passing A_f writes since R20).
// Waves (512 thr, wv i -> SIMD i&3): wv0=h0(Whh0,+x-dot) SIMD0;
// wv1=h1(Whh1) SIMD1; wv2/3=A-burst (Wih1, R20 code) SIMD2/3;
// wv4=y (VALU-only, SIMD0 - complements h0's MFMA); wv5-7 idle.
// Barrier every 4 steps. Schedule: SK1=24, A@s=19+16k (ub=s-19, gap 4..19),
// y@s=45+16k (t=s-45+slot, gap 30..45). Audited: all producer->consumer
// window gaps >=5 (strict barrier separation at width 4); ring slots
// disjoint mod 32 (h0[t] live t..t+19 vs rewrite t+32; A[u] read u+24,
// rewrite u+36..; h1[t] read <=t+45, rewrite t+56). NSTEP=1024 (mult of 4).

#define TT    1000
#define TIN   800
#define HD    128
#define NF    5
#define BATCH 256
#define RS    136           // h16 ring row stride (272B = 17x16B)
#define AS    132           // f32 A-ring row stride (528B)
#define SK1   24            // h1[u] computed at step u+24
#define NSTEP 1024          // TT + SK1, multiple of 4
#define AOFF  19            // A bursts at s = 19+16k
#define YOFF  45            // y bursts at s = 45+16k

typedef _Float16 h16x2 __attribute__((ext_vector_type(2)));
typedef _Float16 h16x8 __attribute__((ext_vector_type(8)));
typedef float    f32x4 __attribute__((ext_vector_type(4)));

template<int CTRL>
__device__ __forceinline__ float dpp_mov(float v) {
    union { float f; int i; } u, r;
    u.f = v;
    r.i = __builtin_amdgcn_update_dpp(0, u.i, CTRL, 0xF, 0xF, true);
    return r.f;
}

__global__ __launch_bounds__(512, 1) void rnn_mf(
    const float* __restrict__ x,        // [256,800,5]
    const float* __restrict__ h_state,  // [2,256,128]
    const float* __restrict__ w_ih0,    // [128,5]
    const float* __restrict__ w_hh0,    // [128,128]
    const float* __restrict__ b_ih0,    // [128]
    const float* __restrict__ b_hh0,    // [128]
    const float* __restrict__ w_ih1,    // [128,128]
    const float* __restrict__ w_hh1,    // [128,128]
    const float* __restrict__ b_ih1,    // [128]
    const float* __restrict__ b_hh1,    // [128]
    const float* __restrict__ w_out,    // [1,128]
    const float* __restrict__ b_out,    // [1]
    float* __restrict__ out)            // [204800 y] ++ [65536 final states]
{
    __shared__ __align__(16) _Float16 x_h[TIN * 8];      // 12.8 KB
    __shared__ __align__(16) _Float16 ring0[32][RS];     // h0 history
    __shared__ __align__(16) _Float16 ring1[32][RS];     // h1 history
    __shared__ __align__(16) float    A_f[32][AS];       // Wih1.h0 ring
    __shared__ float y_lds[TIN];

    const int tid  = threadIdx.x;
    const int bb   = blockIdx.x;
    const int wv   = tid >> 6;          // wave id 0..7 (SIMD = wv&3)
    const int lane = tid & 63;
    const int l4   = lane >> 4;         // 0..3
    const int cc   = lane & 15;         // 0..15
    const int mt_w = cc >> 1;           // owned mtile (0..7)
    const int rp_w = (cc & 1) * 2;      // owned reg pair (0 or 2)
    const int base = mt_w * 16 + l4 * 4 + rp_w;  // owned rows base, base+1

    // ---- stage x[bb] into LDS (fp16, stride 8, pads zero) ----
    for (int i = tid; i < TIN * 8; i += 512) x_h[i] = (_Float16)0.f;
    __syncthreads();
    for (int i = tid; i < TIN * NF; i += 512) {
        int t = i / 5, f = i - 5 * t;
        x_h[t * 8 + f] = (_Float16)x[bb * (TIN * NF) + i];
    }
    if (tid < HD) {
        ring0[31][tid] = (_Float16)h_state[bb * HD + tid];              // h0[-1]
        ring1[31][tid] = (_Float16)h_state[BATCH * HD + bb * HD + tid]; // h1[-1]
    }

    // ---- weight store: 128-VGPR block shared across wave roles ----
    union WU {
        h16x8 af[8][4];     // wv0: Whh0, wv1: Whh1 (full 128 rows)
        h16x8 ai[4][4];     // wv2,3: Wih1 half (64 rows)
    } W;
    h16x2 wo[16];           // wv4 only
    h16x2 wxa[3], wxb[3];   // wv0: Wih0 rows base, base+1
    float bias0 = 0.f, bias1 = 0.f;

    if (wv < 2) {
        const float* Wsrc = (wv == 0) ? w_hh0 : w_hh1;
        #pragma unroll
        for (int mt = 0; mt < 8; ++mt) {
            #pragma unroll
            for (int kt = 0; kt < 4; ++kt) {
                const float* rp = Wsrc + (mt * 16 + cc) * HD + kt * 32 + l4 * 8;
                h16x8 v;
                #pragma unroll
                for (int j = 0; j < 8; ++j) v[j] = (_Float16)rp[j];
                W.af[mt][kt] = v;
            }
        }
        if (wv == 0) {
            #pragma unroll
            for (int k = 0; k < 3; ++k) {
                _Float16 a0 = (_Float16)w_ih0[base * NF + 2 * k];
                _Float16 a1 = (2 * k + 1 < NF) ? (_Float16)w_ih0[base * NF + 2 * k + 1] : (_Float16)0.f;
                _Float16 b0 = (_Float16)w_ih0[(base + 1) * NF + 2 * k];
                _Float16 b1 = (2 * k + 1 < NF) ? (_Float16)w_ih0[(base + 1) * NF + 2 * k + 1] : (_Float16)0.f;
                h16x2 wa = { a0, a1 }; wxa[k] = wa;
                h16x2 wb = { b0, b1 }; wxb[k] = wb;
            }
            bias0 = b_ih0[base] + b_hh0[base];
            bias1 = b_ih0[base + 1] + b_hh0[base + 1];
        } else {
            bias0 = b_ih1[base] + b_hh1[base];
            bias1 = b_ih1[base + 1] + b_hh1[base + 1];
        }
    } else if (wv < 4) {
        const int m0 = (wv - 2) * 64;
        #pragma unroll
        for (int mt = 0; mt < 4; ++mt) {
            #pragma unroll
            for (int kt = 0; kt < 4; ++kt) {
                const float* rp = w_ih1 + (m0 + mt * 16 + cc) * HD + kt * 32 + l4 * 8;
                h16x8 v;
                #pragma unroll
                for (int j = 0; j < 8; ++j) v[j] = (_Float16)rp[j];
                W.ai[mt][kt] = v;
            }
        }
    } else if (wv == 4) {
        const int c4 = lane & 3;
        #pragma unroll
        for (int t = 0; t < 16; ++t) {
            h16x2 w2 = { (_Float16)w_out[c4 * 32 + 2 * t],
                         (_Float16)w_out[c4 * 32 + 2 * t + 1] };
            wo[t] = w2;
        }
    }
    const float bout = b_out[0];

    float hfin0 = 0.f, hfin1 = 0.f;

    __syncthreads();

    // MFMA matvec with replicated B: 4 broadcast ds_read_b128, 32 MFMA
    // (8 indep m-chains of 4 K-chained), then cndmask-select owned rows.
    auto hstep = [&](const _Float16* hprev, float& r0, float& r1) {
        h16x8 bf[4];
        #pragma unroll
        for (int kt = 0; kt < 4; ++kt)
            bf[kt] = *(const h16x8*)(hprev + kt * 32 + l4 * 8);
        f32x4 acc[8];
        #pragma unroll
        for (int mt = 0; mt < 8; ++mt) {
            f32x4 a = {0.f, 0.f, 0.f, 0.f};
            #pragma unroll
            for (int kt = 0; kt < 4; ++kt)
                a = __builtin_amdgcn_mfma_f32_16x16x32_f16(W.af[mt][kt], bf[kt], a, 0, 0, 0);
            acc[mt] = a;
        }
        r0 = 0.f; r1 = 0.f;
        #pragma unroll
        for (int mt = 0; mt < 8; ++mt) {
            float e0 = (cc & 1) ? acc[mt][2] : acc[mt][0];
            float e1 = (cc & 1) ? acc[mt][3] : acc[mt][1];
            bool sel = (mt_w == mt);
            r0 = sel ? e0 : r0;
            r1 = sel ? e1 : r1;
        }
    };

    for (int s = 0; s < NSTEP; ++s) {
        if (wv == 0) {
            // h0[s] = relu(Whh0.h0[s-1] + Wih0.x[s] + b)  (wave-internal dep)
            if (s < TT) {
                float v0, v1;
                hstep(&ring0[(s + 31) & 31][0], v0, v1);
                v0 += bias0; v1 += bias1;
                if (s < TIN) {
                    h16x8 xv = *(const h16x8*)(&x_h[s * 8]);
                    h16x2 xp0 = { xv[0], xv[1] };
                    h16x2 xp1 = { xv[2], xv[3] };
                    h16x2 xp2 = { xv[4], xv[5] };   // slot 5 is zero pad
                    float xc0 = __builtin_amdgcn_fdot2(wxa[2], xp2, 0.f, false);
                    xc0 = __builtin_amdgcn_fdot2(wxa[1], xp1, xc0, false);
                    xc0 = __builtin_amdgcn_fdot2(wxa[0], xp0, xc0, false);
                    float xc1 = __builtin_amdgcn_fdot2(wxb[2], xp2, 0.f, false);
                    xc1 = __builtin_amdgcn_fdot2(wxb[1], xp1, xc1, false);
                    xc1 = __builtin_amdgcn_fdot2(wxb[0], xp0, xc1, false);
                    v0 += xc0; v1 += xc1;
                }
                v0 = fmaxf(v0, 0.f);
                v1 = fmaxf(v1, 0.f);
                h16x2 hv = { (_Float16)v0, (_Float16)v1 };
                *(h16x2*)(&ring0[s & 31][base]) = hv;
                if (s == TT - 1) { hfin0 = v0; hfin1 = v1; }
            }
        } else if (wv == 1) {
            // h1[u] = relu(Whh1.h1[u-1] + A[u] + b), u = s - 24
            if (s >= SK1) {
                const int u = s - SK1;
                float v0, v1;
                hstep(&ring1[(u + 31) & 31][0], v0, v1);
                float2 av = *(const float2*)(&A_f[u & 31][base]);
                v0 = fmaxf(v0 + bias0 + av.x, 0.f);
                v1 = fmaxf(v1 + bias1 + av.y, 0.f);
                h16x2 hv = { (_Float16)v0, (_Float16)v1 };
                *(h16x2*)(&ring1[u & 31][base]) = hv;
                if (u == TT - 1) { hfin0 = v0; hfin1 = v1; }
            }
        } else if (wv < 4) {
            // A burst: A[ub..ub+15] = Wih1 . h0[ub..ub+15], ub = s-19
            if (s >= AOFF && s <= 1011 && ((s - AOFF) & 15) == 0) {
                const int m0 = (wv - 2) * 64;
                const int ub = s - AOFF;
                const int un = ub + cc;             // this lane's column step
                h16x8 bf[4];
                #pragma unroll
                for (int kt = 0; kt < 4; ++kt)
                    bf[kt] = *(const h16x8*)(&ring0[un & 31][kt * 32 + l4 * 8]);
                #pragma unroll
                for (int mt = 0; mt < 4; ++mt) {
                    f32x4 acc = {0.f, 0.f, 0.f, 0.f};
                    #pragma unroll
                    for (int kt = 0; kt < 4; ++kt)
                        acc = __builtin_amdgcn_mfma_f32_16x16x32_f16(
                            W.ai[mt][kt], bf[kt], acc, 0, 0, 0);
                    if (un < TT)
                        *(f32x4*)(&A_f[un & 31][m0 + mt * 16 + l4 * 4]) = acc;
                }
            }
        } else if (wv == 4) {
            // y burst: t = (s-45)+slot; h1[t] written at t+24 <= s-6
            if (s >= YOFF && s <= 829 && ((s - YOFF) & 15) == 0) {
                const int slot = lane >> 2;
                const int c4   = lane & 3;
                const int t    = (s - YOFF) + slot;
                const _Float16* rb = &ring1[t & 31][0] + c4 * 32;
                float z = 0.f;
                #pragma unroll
                for (int u2 = 0; u2 < 4; ++u2) {
                    h16x8 hv = *(const h16x8*)(rb + 8 * u2);
                    h16x2 hp0 = { hv[0], hv[1] };
                    h16x2 hp1 = { hv[2], hv[3] };
                    h16x2 hp2 = { hv[4], hv[5] };
                    h16x2 hp3 = { hv[6], hv[7] };
                    z = __builtin_amdgcn_fdot2(wo[4 * u2 + 0], hp0, z, false);
                    z = __builtin_amdgcn_fdot2(wo[4 * u2 + 1], hp1, z, false);
                    z = __builtin_amdgcn_fdot2(wo[4 * u2 + 2], hp2, z, false);
                    z = __builtin_amdgcn_fdot2(wo[4 * u2 + 3], hp3, z, false);
                }
                z += dpp_mov<0xB1>(z);    // xor1 (within quad)
                z += dpp_mov<0x4E>(z);    // xor2
                if (c4 == 0) y_lds[t] = 1.f / (1.f + expf(-(z + bout)));
            }
        }
        if ((s & 3) == 3) __syncthreads();
    }

    // ---- epilogue: single global dump (last barrier was at s=1023) ----
    for (int i = tid; i < TIN; i += 512)
        out[bb * TIN + i] = y_lds[i];
    if (wv == 0)
        *(float2*)(&out[TIN * BATCH + bb * HD + base]) = make_float2(hfin0, hfin1);
    else if (wv == 1)
        *(float2*)(&out[TIN * BATCH + BATCH * HD + bb * HD + base]) = make_float2(hfin0, hfin1);
}

extern "C" void kernel_launch(void* const* d_in, const int* in_sizes, int n_in,
                              void* d_out, int out_size, void* d_ws, size_t ws_size,
                              hipStream_t stream) {
    (void)in_sizes; (void)n_in; (void)d_ws; (void)ws_size; (void)out_size;
    rnn_mf<<<dim3(BATCH), dim3(512), 0, stream>>>(
        (const float*)d_in[0],  (const float*)d_in[1],
        (const float*)d_in[2],  (const float*)d_in[3],
        (const float*)d_in[4],  (const float*)d_in[5],
        (const float*)d_in[6],  (const float*)d_in[7],
        (const float*)d_in[8],  (const float*)d_in[9],
        (const float*)d_in[10], (const float*)d_in[11],
        (float*)d_out);
}

// Round 8
// 428.850 us; speedup vs baseline: 1.3506x; 1.3506x over previous
//
#include <hip/hip_runtime.h>
#include <math.h>

// 2-layer ReLU RNN, B=256, T=1000 (input 800 + zero pad), H=128, F=5.
// R23 = R20 (champion, 377us rocprof) + two convoy/critical-path trims:
//  1) 8 waves -> 6 (384 thr): idle wv7 deleted; y folded into A-wave wv4.
//     Burst phases staggered mod 16: A@1 (s=17+16k), y@5 (s=37+16k),
//     xc@9 (s=9+16k) -> at most ONE burst wave per step.
//  2) x-dot removed from the critical h0 engine: xc[t]=Wih0.x[t] is
//     input-only, precomputed by wv5 in 16-step bursts into a 32-deep f32
//     ring (prologue covers t=0..15; burst at s=9+16k makes t=16+16k..31+16k,
//     ready >=7 steps early; slot reuse gap >=10). h0 engine reads ONE f32.
// Everything else is R20 verbatim (engine matvec, DPP tree, A-MFMA with
// m89-verified layouts, ring offsets SK1=20 / A@ub=s-17 / y@t=s-37+slot,
// all ring windows re-audited unchanged).
// Model (fits R15/R20/R21/R22): step ~= crit-wave issue + serial latency
// (~250) + barrier machinery (~300@8w). R22 refuted MFMA-recurrence
// (1271 cyc/step: dependent MFMA latency > fdot2 issue). Flag-polling
// (R9/R12/R13) and self-contained engines (R21) also dead.

#define TT    1000
#define TIN   800
#define HD    128
#define NF    5
#define BATCH 256
#define RS    136           // h16 ring row stride (272B = 17x16B)
#define AS    132           // f32 ring row stride (528B = 33x16B)
#define SK1   20            // h1[u] computed at step u+20
#define NSTEP (TT + SK1)    // 1020 steps

typedef _Float16 h16x2 __attribute__((ext_vector_type(2)));
typedef _Float16 h16x8 __attribute__((ext_vector_type(8)));
typedef float    f32x4 __attribute__((ext_vector_type(4)));

template<int CTRL>
__device__ __forceinline__ float dpp_mov(float v) {
    union { float f; int i; } u, r;
    u.f = v;
    r.i = __builtin_amdgcn_update_dpp(0, u.i, CTRL, 0xF, 0xF, true);
    return r.f;
}

__global__ __launch_bounds__(384, 1) void rnn_c6(
    const float* __restrict__ x,        // [256,800,5]
    const float* __restrict__ h_state,  // [2,256,128]
    const float* __restrict__ w_ih0,    // [128,5]
    const float* __restrict__ w_hh0,    // [128,128]
    const float* __restrict__ b_ih0,    // [128]
    const float* __restrict__ b_hh0,    // [128]
    const float* __restrict__ w_ih1,    // [128,128]
    const float* __restrict__ w_hh1,    // [128,128]
    const float* __restrict__ b_ih1,    // [128]
    const float* __restrict__ b_hh1,    // [128]
    const float* __restrict__ w_out,    // [1,128]
    const float* __restrict__ b_out,    // [1]
    float* __restrict__ out)            // [204800 y] ++ [65536 final states]
{
    __shared__ __align__(16) _Float16 x_h[TIN * 8];      // 12.8 KB
    __shared__ __align__(16) _Float16 ring0[32][RS];     // h0 history
    __shared__ __align__(16) _Float16 ring1[32][RS];     // h1 history
    __shared__ __align__(16) float    A_f[32][AS];       // Wih1.h0 ring
    __shared__ __align__(16) float    xc_f[32][AS];      // Wih0.x ring (f32)
    __shared__ float y_lds[TIN];

    const int tid  = threadIdx.x;
    const int bb   = blockIdx.x;
    const int wv   = tid >> 6;          // wave id 0..5 (SIMD = wv&3)
    const int lane = tid & 63;

    // ---- stage x[bb] into LDS (fp16, stride 8, pads zero) ----
    for (int i = tid; i < TIN * 8; i += 384) x_h[i] = (_Float16)0.f;
    __syncthreads();
    for (int i = tid; i < TIN * NF; i += 384) {
        int t = i / 5, f = i - 5 * t;
        x_h[t * 8 + f] = (_Float16)x[bb * (TIN * NF) + i];
    }
    if (tid < HD) {
        ring0[31][tid] = (_Float16)h_state[bb * HD + tid];              // h0[-1]
        ring1[31][tid] = (_Float16)h_state[BATCH * HD + bb * HD + tid]; // h1[-1]
    }

    // ---- h-engine lane geometry (wv 0..3) ----
    const int c    = lane & 3;                      // col chunk (32 cols)
    const int rg   = lane >> 2;                     // row group (4 rows)
    const int g    = 2 * (c & 1) + ((c >> 1) & 1);  // XOR row map (2-bit)
    const int half = wv & 1;
    const int row  = half * 64 + rg * 4 + g;        // lane's final row

    // ---- weight store: 64-VGPR block shared across wave roles ----
    union WU {
        h16x2 wp[4][16];    // wv0-3: rows half*64+rg*4+(j^g), cols c*32..+31
        h16x8 af[4][4];     // wv4,5: Wih1 MFMA A-frags (64-row half)
    } W;
    h16x2 wo[16];           // wv4: wout cols (lane&3)*32..+31
    h16x2 xwa[3], xwb[3];   // wv5: Wih0 rows 2*lane, 2*lane+1
    float bias = 0.f;

    if (wv < 4) {
        const float* Wsrc = (wv < 2) ? w_hh0 : w_hh1;
        #pragma unroll
        for (int j = 0; j < 4; ++j) {
            const float* rp = Wsrc + (half * 64 + rg * 4 + (j ^ g)) * HD + c * 32;
            #pragma unroll
            for (int t = 0; t < 16; ++t) {
                h16x2 w2 = { (_Float16)rp[2 * t], (_Float16)rp[2 * t + 1] };
                W.wp[j][t] = w2;
            }
        }
        bias = (wv < 2) ? (b_ih0[row] + b_hh0[row])
                        : (b_ih1[row] + b_hh1[row]);
    } else {
        // A-frag (16x16x32): lane holds A[m = m0 + mt*16 + (lane&15)]
        //                                [k = kt*32 + (lane>>4)*8 + j]
        const int m0 = (wv == 4) ? 0 : 64;
        #pragma unroll
        for (int mt = 0; mt < 4; ++mt) {
            #pragma unroll
            for (int kt = 0; kt < 4; ++kt) {
                const float* rp = w_ih1 + (m0 + mt * 16 + (lane & 15)) * HD
                                + kt * 32 + (lane >> 4) * 8;
                h16x8 v;
                #pragma unroll
                for (int j = 0; j < 8; ++j) v[j] = (_Float16)rp[j];
                W.af[mt][kt] = v;
            }
        }
        if (wv == 4) {
            const int c4 = lane & 3;
            #pragma unroll
            for (int t = 0; t < 16; ++t) {
                h16x2 w2 = { (_Float16)w_out[c4 * 32 + 2 * t],
                             (_Float16)w_out[c4 * 32 + 2 * t + 1] };
                wo[t] = w2;
            }
        } else {
            #pragma unroll
            for (int k = 0; k < 3; ++k) {
                _Float16 a0 = (_Float16)w_ih0[(2 * lane) * NF + 2 * k];
                _Float16 a1 = (2 * k + 1 < NF) ? (_Float16)w_ih0[(2 * lane) * NF + 2 * k + 1] : (_Float16)0.f;
                _Float16 b0 = (_Float16)w_ih0[(2 * lane + 1) * NF + 2 * k];
                _Float16 b1 = (2 * k + 1 < NF) ? (_Float16)w_ih0[(2 * lane + 1) * NF + 2 * k + 1] : (_Float16)0.f;
                h16x2 wa = { a0, a1 }; xwa[k] = wa;
                h16x2 wb = { b0, b1 }; xwb[k] = wb;
            }
        }
    }
    const float bout = b_out[0];

    float hfin = 0.f;

    __syncthreads();

    // xc burst: lane owns rows 2*lane, 2*lane+1; 16 t's per burst.
    auto xc_burst = [&](int tb) {
        #pragma unroll
        for (int ti = 0; ti < 16; ++ti) {
            const int t = tb + ti;          // uniform across lanes
            h16x8 xv = *(const h16x8*)(&x_h[t * 8]);
            h16x2 xp0 = { xv[0], xv[1] };
            h16x2 xp1 = { xv[2], xv[3] };
            h16x2 xp2 = { xv[4], xv[5] };   // slot 5 is zero pad
            float c0 = __builtin_amdgcn_fdot2(xwa[2], xp2, 0.f, false);
            c0 = __builtin_amdgcn_fdot2(xwa[1], xp1, c0, false);
            c0 = __builtin_amdgcn_fdot2(xwa[0], xp0, c0, false);
            float c1 = __builtin_amdgcn_fdot2(xwb[2], xp2, 0.f, false);
            c1 = __builtin_amdgcn_fdot2(xwb[1], xp1, c1, false);
            c1 = __builtin_amdgcn_fdot2(xwb[0], xp0, c1, false);
            *(float2*)(&xc_f[t & 31][2 * lane]) = make_float2(c0, c1);
        }
    };

    if (wv == 5) xc_burst(0);       // prologue: t = 0..15
    __syncthreads();

    // Tiled matvec (R20-verified): 4 ds_read_b128, 4 rows x 16 fdot2,
    // 2-level DPP tree -> full sum for row rg*4+g.
    auto matvec = [&](const _Float16* base) -> float {
        h16x8 hv[4];
        #pragma unroll
        for (int u2 = 0; u2 < 4; ++u2)
            hv[u2] = *(const h16x8*)(base + c * 32 + 8 * u2);
        float a[4] = {0.f, 0.f, 0.f, 0.f};
        #pragma unroll
        for (int j = 0; j < 4; ++j) {
            float aj = 0.f;
            #pragma unroll
            for (int t = 0; t < 16; ++t) {
                h16x2 hp = { hv[t >> 2][2 * (t & 3)], hv[t >> 2][2 * (t & 3) + 1] };
                aj = __builtin_amdgcn_fdot2(W.wp[j][t], hp, aj, false);
            }
            a[j] = aj;
        }
        a[0] += dpp_mov<0xB1>(a[2]);    // level1 (lane^1, g flips bit1)
        a[1] += dpp_mov<0xB1>(a[3]);
        a[0] += dpp_mov<0x4E>(a[1]);    // level2 (lane^2, g flips bit0)
        return a[0];
    };

    for (int s = 0; s < NSTEP; ++s) {
        if (wv < 2) {
            // h0[s] = relu(Whh0.h0[s-1] + xc[s] + b)
            if (s < TT) {
                float v = matvec(&ring0[(s + 31) & 31][0]) + bias;
                if (s < TIN) v += xc_f[s & 31][row];
                v = fmaxf(v, 0.f);
                ring0[s & 31][row] = (_Float16)v;
                if (s == TT - 1) hfin = v;
            }
        } else if (wv < 4) {
            // h1[u] = relu(Whh1.h1[u-1] + A[u] + b), u = s - 20
            if (s >= SK1) {
                const int u = s - SK1;
                float v = matvec(&ring1[(u + 31) & 31][0]);
                v = fmaxf(v + bias + A_f[u & 31][row], 0.f);
                ring1[u & 31][row] = (_Float16)v;
                if (u == TT - 1) hfin = v;
            }
        } else {
            // A burst (both wv4, wv5): A[ub..ub+15] = Wih1 . h0[..], ub=s-17
            if (s >= 17 && s <= 1009 && ((s - 17) & 15) == 0) {
                const int m0 = (wv == 4) ? 0 : 64;
                const int ub = s - 17;
                const int un = ub + (lane & 15);    // this lane's column step
                h16x8 bf[4];
                #pragma unroll
                for (int kt = 0; kt < 4; ++kt)
                    bf[kt] = *(const h16x8*)(&ring0[un & 31]
                                             [kt * 32 + (lane >> 4) * 8]);
                #pragma unroll
                for (int mt = 0; mt < 4; ++mt) {
                    f32x4 acc = {0.f, 0.f, 0.f, 0.f};
                    #pragma unroll
                    for (int kt = 0; kt < 4; ++kt)
                        acc = __builtin_amdgcn_mfma_f32_16x16x32_f16(
                            W.af[mt][kt], bf[kt], acc, 0, 0, 0);
                    if (un < TT)
                        *(f32x4*)(&A_f[un & 31]
                                  [m0 + mt * 16 + (lane >> 4) * 4]) = acc;
                }
            }
            if (wv == 4) {
                // y burst: t = (s-37)+slot; h1[t] written at t+20 <= s-2
                if (s >= 37 && s <= 821 && ((s - 37) & 15) == 0) {
                    const int slot = lane >> 2;
                    const int c4   = lane & 3;
                    const int t    = (s - 37) + slot;
                    const _Float16* rb = &ring1[t & 31][0] + c4 * 32;
                    float z = 0.f;
                    #pragma unroll
                    for (int u2 = 0; u2 < 4; ++u2) {
                        h16x8 hv = *(const h16x8*)(rb + 8 * u2);
                        h16x2 hp0 = { hv[0], hv[1] };
                        h16x2 hp1 = { hv[2], hv[3] };
                        h16x2 hp2 = { hv[4], hv[5] };
                        h16x2 hp3 = { hv[6], hv[7] };
                        z = __builtin_amdgcn_fdot2(wo[4 * u2 + 0], hp0, z, false);
                        z = __builtin_amdgcn_fdot2(wo[4 * u2 + 1], hp1, z, false);
                        z = __builtin_amdgcn_fdot2(wo[4 * u2 + 2], hp2, z, false);
                        z = __builtin_amdgcn_fdot2(wo[4 * u2 + 3], hp3, z, false);
                    }
                    z += dpp_mov<0xB1>(z);    // xor1 (within quad)
                    z += dpp_mov<0x4E>(z);    // xor2
                    if (c4 == 0) y_lds[t] = 1.f / (1.f + expf(-(z + bout)));
                }
            } else {
                // xc burst: t = 16+16k..31+16k at s = 9+16k (>=7 steps early)
                if (s >= 9 && s <= 777 && ((s - 9) & 15) == 0) {
                    xc_burst(s + 7);
                }
            }
        }
        __syncthreads();
    }

    // ---- epilogue: single global dump ----
    for (int i = tid; i < TIN; i += 384)
        out[bb * TIN + i] = y_lds[i];
    if (wv < 2)
        out[TIN * BATCH + bb * HD + row] = hfin;
    else if (wv < 4)
        out[TIN * BATCH + BATCH * HD + bb * HD + row] = hfin;
}

extern "C" void kernel_launch(void* const* d_in, const int* in_sizes, int n_in,
                              void* d_out, int out_size, void* d_ws, size_t ws_size,
                              hipStream_t stream) {
    (void)in_sizes; (void)n_in; (void)d_ws; (void)ws_size; (void)out_size;
    rnn_c6<<<dim3(BATCH), dim3(384), 0, stream>>>(
        (const float*)d_in[0],  (const float*)d_in[1],
        (const float*)d_in[2],  (const float*)d_in[3],
        (const float*)d_in[4],  (const float*)d_in[5],
        (const float*)d_in[6],  (const float*)d_in[7],
        (const float*)d_in[8],  (const float*)d_in[9],
        (const float*)d_in[10], (const float*)d_in[11],
        (float*)d_out);
}